// Round 1
// baseline (153.520 us; speedup 1.0000x reference)
//
#include <hip/hip_runtime.h>
#include <hip/hip_bf16.h>

// SignedAttention: B=4,H=8,L=2048,D=64, N_PATCHES=128 (16 ch/patch), window: patches p+1..p+9.
// One block per (bh, patch). 256 threads = 4 waves. bf16 MFMA for QK^T and PV, fp32 softmax.

#define LSEQ   2048
#define DIM    64
#define CH     16
#define NPATCH 128
#define WIN    9      // valid patch offsets 1..9
#define MAXK   144
#define KPAD   160    // padded key-dim for PV mfma k-steps (multiple of 32)

// LDS row strides (elements) — chosen to break bank conflicts while keeping 16B alignment
#define SQ 72
#define SK 72
#define SV 168
#define SS 164
#define SA 168

typedef __attribute__((ext_vector_type(8))) short bf16x8;
typedef __attribute__((ext_vector_type(4))) float f32x4;

__device__ __forceinline__ unsigned short f2bf1(float a) {
  unsigned int u = __float_as_uint(a);
  u = (u + 0x7fffu + ((u >> 16) & 1u)) >> 16;   // RNE
  return (unsigned short)u;
}

__device__ __forceinline__ unsigned int pack2bf(float a, float b) {
  unsigned int ua = __float_as_uint(a);
  unsigned int ub = __float_as_uint(b);
  ua = (ua + 0x7fffu + ((ua >> 16) & 1u)) >> 16;
  ub = (ub + 0x7fffu + ((ub >> 16) & 1u)) & 0xffff0000u;
  return ua | ub;
}

__global__ __launch_bounds__(256, 2)
void signed_attn_kernel(const float* __restrict__ Q,
                        const float* __restrict__ K,
                        const float* __restrict__ V,
                        const float* __restrict__ LS,
                        float* __restrict__ O) {
  __shared__ __align__(16) unsigned short Qs[16 * SQ];
  __shared__ __align__(16) unsigned short Ks[MAXK * SK];
  __shared__ __align__(16) unsigned short Vt[DIM * SV];   // Vt[d][c] = V[c][d]
  __shared__ __align__(16) float          Sf[16 * SS];    // scores, then exp(pos)
  __shared__ __align__(16) float          En[16 * SS];    // exp(neg)
  __shared__ __align__(16) unsigned short As[16 * SA];    // A in bf16, zero-padded to KPAD

  const int p  = blockIdx.x & (NPATCH - 1);
  const int bh = blockIdx.x >> 7;
  const int t  = threadIdx.x;

  float* Og = O + ((size_t)bh * LSEQ + (size_t)p * CH) * DIM;

  const int npk = (NPATCH - 1 - p) < WIN ? (NPATCH - 1 - p) : WIN;
  const int nk  = npk * CH;

  if (nk == 0) {          // last patch: everything masked -> softmaxes cancel -> 0
    for (int e = t; e < CH * DIM; e += 256) Og[e] = 0.f;
    return;
  }

  const float scale = fminf(30.f, fmaxf(1.f, __expf(LS[0]))) * 0.125f; // /sqrt(64)

  const float4* Qg = (const float4*)(Q + ((size_t)bh * LSEQ + (size_t)p * CH) * DIM);
  const float4* Kg = (const float4*)(K + ((size_t)bh * LSEQ + (size_t)(p + 1) * CH) * DIM);
  const float4* Vg = (const float4*)(V + ((size_t)bh * LSEQ + (size_t)(p + 1) * CH) * DIM);

  // ---- stage Q (16x64) as bf16: exactly 1 float4 per thread ----
  {
    int row = t >> 4, d4 = t & 15;
    float4 v = Qg[t];
    *(uint2*)&Qs[row * SQ + d4 * 4] =
        make_uint2(pack2bf(v.x, v.y), pack2bf(v.z, v.w));
  }
  // ---- stage K (nk x 64) ----
  for (int e = t; e < nk * 16; e += 256) {
    int row = e >> 4, d4 = e & 15;
    float4 v = Kg[e];
    *(uint2*)&Ks[row * SK + d4 * 4] =
        make_uint2(pack2bf(v.x, v.y), pack2bf(v.z, v.w));
  }
  // ---- stage V transposed: Vt[d][c], 4 key-rows at a time so stores are 8B ----
  {
    const int nq = nk >> 2;
    for (int e = t; e < nq * 16; e += 256) {
      int cq = e >> 4, d4 = e & 15;
      int c = cq << 2;
      float4 v0 = Vg[(c + 0) * 16 + d4];
      float4 v1 = Vg[(c + 1) * 16 + d4];
      float4 v2 = Vg[(c + 2) * 16 + d4];
      float4 v3 = Vg[(c + 3) * 16 + d4];
      int db = d4 << 2;
      *(uint2*)&Vt[(db + 0) * SV + c] = make_uint2(pack2bf(v0.x, v1.x), pack2bf(v2.x, v3.x));
      *(uint2*)&Vt[(db + 1) * SV + c] = make_uint2(pack2bf(v0.y, v1.y), pack2bf(v2.y, v3.y));
      *(uint2*)&Vt[(db + 2) * SV + c] = make_uint2(pack2bf(v0.z, v1.z), pack2bf(v2.z, v3.z));
      *(uint2*)&Vt[(db + 3) * SV + c] = make_uint2(pack2bf(v0.w, v1.w), pack2bf(v2.w, v3.w));
    }
  }
  // zero-fill Vt cols [nk, KPAD) so PV k-steps read zeros
  {
    int d = t & 63;
    for (int c = nk + (t >> 6); c < KPAD; c += 4) Vt[d * SV + c] = 0;
  }

  __syncthreads();

  const int w  = t >> 6;     // wave id 0..3
  const int l  = t & 63;
  const int lr = l & 15;
  const int q4 = l >> 4;

  // ---- QK^T: wave w computes key-tiles w, w+4, w+8 ----
  for (int tl = w; tl < npk; tl += 4) {
    f32x4 acc = {0.f, 0.f, 0.f, 0.f};
#pragma unroll
    for (int s = 0; s < 2; s++) {
      bf16x8 a = *(const bf16x8*)&Qs[lr * SQ + q4 * 8 + 32 * s];
      bf16x8 b = *(const bf16x8*)&Ks[(tl * 16 + lr) * SK + q4 * 8 + 32 * s];
      acc = __builtin_amdgcn_mfma_f32_16x16x32_bf16(a, b, acc, 0, 0, 0);
    }
#pragma unroll
    for (int r = 0; r < 4; r++)
      Sf[(q4 * 4 + r) * SS + tl * 16 + lr] = acc[r];   // C/D: col=lane&15, row=quad*4+reg
  }

  __syncthreads();

  // ---- dual softmax: thread (r, cl) owns cols cl, cl+16, ... of row r ----
  {
    const int r  = t >> 4;
    const int cl = t & 15;
    float smax = -1e30f, smin = 1e30f;
    for (int c = cl; c < nk; c += 16) {
      float s = Sf[r * SS + c];
      smax = fmaxf(smax, s);
      smin = fminf(smin, s);
    }
#pragma unroll
    for (int off = 1; off < 16; off <<= 1) {
      smax = fmaxf(smax, __shfl_xor(smax, off, 64));
      smin = fminf(smin, __shfl_xor(smin, off, 64));
    }
    const float mp = scale * smax;    // max of scale*s
    const float mn = -scale * smin;   // max of -scale*s
    float sp = 0.f, sn = 0.f;
    for (int c = cl; c < nk; c += 16) {
      float s  = Sf[r * SS + c];
      float e1 = __expf(scale * s - mp);
      float e2 = __expf(-scale * s - mn);
      Sf[r * SS + c] = e1;
      En[r * SS + c] = e2;
      sp += e1; sn += e2;
    }
#pragma unroll
    for (int off = 1; off < 16; off <<= 1) {
      sp += __shfl_xor(sp, off, 64);
      sn += __shfl_xor(sn, off, 64);
    }
    const float rp = 1.0f / sp;
    const float rn = 1.0f / sn;
    for (int c = cl; c < KPAD; c += 16) {
      float a = 0.f;
      if (c < nk) a = Sf[r * SS + c] * rp - En[r * SS + c] * rn;
      As[r * SA + c] = f2bf1(a);
    }
  }

  __syncthreads();

  // ---- PV: wave w computes output cols [16w, 16w+16); contraction over keys ----
  {
    const int ksteps = (nk + 31) >> 5;
    f32x4 acc = {0.f, 0.f, 0.f, 0.f};
    for (int s = 0; s < ksteps; s++) {
      bf16x8 a = *(const bf16x8*)&As[lr * SA + q4 * 8 + 32 * s];
      bf16x8 b = *(const bf16x8*)&Vt[(w * 16 + lr) * SV + q4 * 8 + 32 * s];
      acc = __builtin_amdgcn_mfma_f32_16x16x32_bf16(a, b, acc, 0, 0, 0);
    }
#pragma unroll
    for (int r = 0; r < 4; r++)
      Og[(q4 * 4 + r) * DIM + w * 16 + lr] = acc[r];
  }
}

extern "C" void kernel_launch(void* const* d_in, const int* in_sizes, int n_in,
                              void* d_out, int out_size, void* d_ws, size_t ws_size,
                              hipStream_t stream) {
  const float* Q  = (const float*)d_in[0];
  const float* K  = (const float*)d_in[1];
  const float* V  = (const float*)d_in[2];
  const float* LS = (const float*)d_in[3];
  float* O = (float*)d_out;
  // 4*8 (bh) * 128 (patches) = 4096 blocks
  signed_attn_kernel<<<dim3(4096), dim3(256), 0, stream>>>(Q, K, V, LS, O);
}

// Round 2
// 110.154 us; speedup vs baseline: 1.3937x; 1.3937x over previous
//
#include <hip/hip_runtime.h>
#include <hip/hip_bf16.h>

// SignedAttention: B=4,H=8,L=2048,D=64; N_PATCHES=128 (16 ch/patch); keys = patches p+1..p+9.
// Round 2: 4 query patches per block (one per wave), K/V staged once for the 12-patch union.
// Scores + dual softmax entirely in registers (shfl reductions); single __syncthreads.

#define LSEQ   2048
#define DIM    64
#define CH     16
#define NPATCH 128
#define WIN    9
#define GRP    4       // query patches per block
#define KBMAX  192     // staged key rows (12 patches)
#define VCOLS  208     // Vt cols zero-filled through here (max read = 16*3 + 160)

// LDS pitches (elements). All row-strides are multiples of 8 elems (16B) so b128 reads
// are aligned; values chosen so b128 read conflicts are <=2-way (free per m136).
#define SK 72    // 144B = 36 dw == 4 mod 32
#define SV 216   // 432B = 108 dw == 12 mod 32
#define SA 168   // 336B = 84 dw == 20 mod 32

typedef __attribute__((ext_vector_type(8))) short bf16x8;
typedef __attribute__((ext_vector_type(4))) float f32x4;

__device__ __forceinline__ unsigned short f2bf1(float a) {
  unsigned int u = __float_as_uint(a);
  u = (u + 0x7fffu + ((u >> 16) & 1u)) >> 16;   // RNE
  return (unsigned short)u;
}

__device__ __forceinline__ unsigned int pack2bf(float a, float b) {
  unsigned int ua = __float_as_uint(a);
  unsigned int ub = __float_as_uint(b);
  ua = (ua + 0x7fffu + ((ua >> 16) & 1u)) >> 16;
  ub = (ub + 0x7fffu + ((ub >> 16) & 1u)) & 0xffff0000u;
  return ua | ub;
}

__device__ __forceinline__ bf16x8 pack8(float4 a, float4 b) {
  bf16x8 r;
  r[0] = (short)f2bf1(a.x); r[1] = (short)f2bf1(a.y);
  r[2] = (short)f2bf1(a.z); r[3] = (short)f2bf1(a.w);
  r[4] = (short)f2bf1(b.x); r[5] = (short)f2bf1(b.y);
  r[6] = (short)f2bf1(b.z); r[7] = (short)f2bf1(b.w);
  return r;
}

__global__ __launch_bounds__(256, 2)
void signed_attn_kernel(const float* __restrict__ Q,
                        const float* __restrict__ K,
                        const float* __restrict__ V,
                        const float* __restrict__ LS,
                        float* __restrict__ O) {
  __shared__ __align__(16) unsigned short Ks[KBMAX * SK];
  __shared__ __align__(16) unsigned short Vt[DIM * SV];        // Vt[d][c] = V[c][d]
  __shared__ __align__(16) unsigned short As[GRP * 16 * SA];   // per-wave A (bf16)

  const int g  = blockIdx.x & 31;       // patch group
  const int bh = blockIdx.x >> 5;
  const int t  = threadIdx.x;
  const int p0 = g * GRP;

  const int kbp = (127 - p0) < 12 ? (127 - p0) : 12;  // staged key patches
  const int kb  = kbp * CH;                           // staged key rows (<=192)

  const float4* Kg = (const float4*)(K + ((size_t)bh * LSEQ + (size_t)(p0 + 1) * CH) * DIM);
  const float4* Vg = (const float4*)(V + ((size_t)bh * LSEQ + (size_t)(p0 + 1) * CH) * DIM);

  // ---- stage K (kb x 64) as bf16, row-major ----
  for (int e = t; e < kb * 16; e += 256) {
    int row = e >> 4, d4 = e & 15;
    float4 v = Kg[e];
    *(uint2*)&Ks[row * SK + d4 * 4] =
        make_uint2(pack2bf(v.x, v.y), pack2bf(v.z, v.w));
  }
  // ---- stage V transposed: Vt[d][c] ----
  {
    const int nq = kb >> 2;
    for (int e = t; e < nq * 16; e += 256) {
      int cq = e >> 4, d4 = e & 15;
      int c = cq << 2;
      float4 v0 = Vg[(c + 0) * 16 + d4];
      float4 v1 = Vg[(c + 1) * 16 + d4];
      float4 v2 = Vg[(c + 2) * 16 + d4];
      float4 v3 = Vg[(c + 3) * 16 + d4];
      int db = d4 << 2;
      *(uint2*)&Vt[(db + 0) * SV + c] = make_uint2(pack2bf(v0.x, v1.x), pack2bf(v2.x, v3.x));
      *(uint2*)&Vt[(db + 1) * SV + c] = make_uint2(pack2bf(v0.y, v1.y), pack2bf(v2.y, v3.y));
      *(uint2*)&Vt[(db + 2) * SV + c] = make_uint2(pack2bf(v0.z, v1.z), pack2bf(v2.z, v3.z));
      *(uint2*)&Vt[(db + 3) * SV + c] = make_uint2(pack2bf(v0.w, v1.w), pack2bf(v2.w, v3.w));
    }
  }
  // zero-fill Vt cols [kb, VCOLS): garbage LDS could be NaN; A=0 * NaN would poison PV
  for (int c = kb + (t >> 6); c < VCOLS; c += 4) Vt[(t & 63) * SV + c] = 0;

  __syncthreads();   // the only barrier; waves are independent below

  const int w  = t >> 6;
  const int l  = t & 63;
  const int lr = l & 15;
  const int q4 = l >> 4;

  const int p   = p0 + w;                              // this wave's query patch
  const int npk = (127 - p) < WIN ? (127 - p) : WIN;   // valid key patches
  float* Og = O + ((size_t)bh * LSEQ + (size_t)p * CH) * DIM;

  if (npk == 0) {   // patch 127: fully masked -> softmaxes cancel -> exact 0
#pragma unroll
    for (int n = 0; n < 4; n++)
#pragma unroll
      for (int r = 0; r < 4; r++)
        Og[(q4 * 4 + r) * DIM + n * 16 + lr] = 0.f;
    return;
  }

  const float scale = fminf(30.f, fmaxf(1.f, __expf(LS[0]))) * 0.125f;
  const int koff = w * CH;   // this wave's key-row offset in the staged window

  // ---- Q fragments straight from global (wave-private) ----
  const float* Qg = Q + ((size_t)bh * LSEQ + (size_t)p * CH) * DIM;
  bf16x8 qa[2];
#pragma unroll
  for (int s = 0; s < 2; s++) {
    const float* qp = Qg + lr * DIM + q4 * 8 + 32 * s;
    qa[s] = pack8(*(const float4*)qp, *(const float4*)(qp + 4));
  }

  // ---- QK^T: 9 tiles, fixed unroll (invalid tiles masked later) ----
  f32x4 sacc[WIN];
#pragma unroll
  for (int tl = 0; tl < WIN; tl++) {
    f32x4 acc = {0.f, 0.f, 0.f, 0.f};
#pragma unroll
    for (int s = 0; s < 2; s++) {
      bf16x8 b = *(const bf16x8*)&Ks[(koff + tl * 16 + lr) * SK + q4 * 8 + 32 * s];
      acc = __builtin_amdgcn_mfma_f32_16x16x32_bf16(qa[s], b, acc, 0, 0, 0);
    }
    sacc[tl] = acc;   // S[row=q4*4+r][col=tl*16+lr]
  }

  // ---- dual softmax in registers; rows live in 16-lane groups ----
  float mx[4], mi[4];
#pragma unroll
  for (int r = 0; r < 4; r++) { mx[r] = -1e30f; mi[r] = 1e30f; }
#pragma unroll
  for (int tl = 0; tl < WIN; tl++) {
    bool val = tl < npk;
#pragma unroll
    for (int r = 0; r < 4; r++) {
      float s = sacc[tl][r];
      mx[r] = fmaxf(mx[r], val ? s : -1e30f);
      mi[r] = fminf(mi[r], val ? s : 1e30f);
    }
  }
#pragma unroll
  for (int off = 1; off < 16; off <<= 1)
#pragma unroll
    for (int r = 0; r < 4; r++) {
      mx[r] = fmaxf(mx[r], __shfl_xor(mx[r], off));
      mi[r] = fminf(mi[r], __shfl_xor(mi[r], off));
    }

  float mp[4], mn[4], sp[4], sn[4];
#pragma unroll
  for (int r = 0; r < 4; r++) {
    mp[r] = scale * mx[r];
    mn[r] = -scale * mi[r];
    sp[r] = 0.f; sn[r] = 0.f;
  }

  f32x4 e2a[WIN];
#pragma unroll
  for (int tl = 0; tl < WIN; tl++) {
    bool val = tl < npk;
#pragma unroll
    for (int r = 0; r < 4; r++) {
      float s  = sacc[tl][r];
      float e1 = __expf(scale * s - mp[r]);
      float e2 = __expf(-scale * s - mn[r]);
      e1 = val ? e1 : 0.f;
      e2 = val ? e2 : 0.f;
      sacc[tl][r] = e1;
      e2a[tl][r]  = e2;
      sp[r] += e1; sn[r] += e2;
    }
  }
#pragma unroll
  for (int off = 1; off < 16; off <<= 1)
#pragma unroll
    for (int r = 0; r < 4; r++) {
      sp[r] += __shfl_xor(sp[r], off);
      sn[r] += __shfl_xor(sn[r], off);
    }

  float rp[4], rn[4];
#pragma unroll
  for (int r = 0; r < 4; r++) { rp[r] = 1.0f / sp[r]; rn[r] = 1.0f / sn[r]; }

  // ---- A -> per-wave LDS (C-layout -> A-operand layout transform) ----
  unsigned short* Aw = As + w * 16 * SA;
#pragma unroll
  for (int tl = 0; tl < WIN; tl++)
#pragma unroll
    for (int r = 0; r < 4; r++) {
      float a = sacc[tl][r] * rp[r] - e2a[tl][r] * rn[r];
      Aw[(q4 * 4 + r) * SA + tl * 16 + lr] = f2bf1(a);
    }
#pragma unroll
  for (int r = 0; r < 4; r++)   // pad tile 9 (cols 144..159) with zeros
    Aw[(q4 * 4 + r) * SA + 144 + lr] = 0;

  // ---- PV: O[16 x 64] = A[16 x 160] * V[160 x 64], 5 fixed k-steps ----
  f32x4 oacc[4] = {{0,0,0,0},{0,0,0,0},{0,0,0,0},{0,0,0,0}};
#pragma unroll
  for (int s = 0; s < 5; s++) {
    bf16x8 a = *(const bf16x8*)&Aw[lr * SA + s * 32 + q4 * 8];
#pragma unroll
    for (int n = 0; n < 4; n++) {
      bf16x8 b = *(const bf16x8*)&Vt[(n * 16 + lr) * SV + koff + s * 32 + q4 * 8];
      oacc[n] = __builtin_amdgcn_mfma_f32_16x16x32_bf16(a, b, oacc[n], 0, 0, 0);
    }
  }
#pragma unroll
  for (int n = 0; n < 4; n++)
#pragma unroll
    for (int r = 0; r < 4; r++)
      Og[(q4 * 4 + r) * DIM + n * 16 + lr] = oacc[n][r];
}

extern "C" void kernel_launch(void* const* d_in, const int* in_sizes, int n_in,
                              void* d_out, int out_size, void* d_ws, size_t ws_size,
                              hipStream_t stream) {
  const float* Q  = (const float*)d_in[0];
  const float* K  = (const float*)d_in[1];
  const float* V  = (const float*)d_in[2];
  const float* LS = (const float*)d_in[3];
  float* O = (float*)d_out;
  // 32 bh * 32 patch-groups = 1024 blocks
  signed_attn_kernel<<<dim3(1024), dim3(256), 0, stream>>>(Q, K, V, LS, O);
}